// Round 12
// baseline (54.369 us; speedup 1.0000x reference)
//
#include <hip/hip_runtime.h>
#include <hip/hip_cooperative_groups.h>

namespace cg = cooperative_groups;

#define NS 32
#define NH 32
#define M_TAB 4096
#define C2L 2.8853900817779268f               // 2*log2(e): e^(2x) = 2^(C2L*x)
#define STEP (31.0f / (float)M_TAB)
#define INV_STEP ((float)M_TAB / 31.0f)

// Single cooperative dispatch: phase 1 tabulates f(t) at 4097 uniform nodes
// (half-wave per node, lane=h), grid.sync(), phase 2 lerps one point/thread.
// 512 blocks x 256 threads = 131072 threads = 4096 nodes x 32 lanes = N points.
__global__ __launch_bounds__(256) void springnn_fused_kernel(
    const float* __restrict__ t_in,
    const float* __restrict__ W1,   // [S][1][H]
    const float* __restrict__ b1,   // [S][H]
    const float* __restrict__ W2,   // [S][H][1]
    const float* __restrict__ b2,   // [S][1]
    float* __restrict__ table,      // d_ws, (M_TAB+1) floats
    float* __restrict__ out,
    int N)
{
    const int gid = blockIdx.x * 256 + threadIdx.x;
    const int h = gid & 31;          // hidden unit (lane)

    // ---- phase 1: tabulate. node 4096 is done by block 0's first half-wave ----
    #pragma unroll
    for (int pass = 0; pass < 2; ++pass) {
        const int g = pass == 0 ? (gid >> 5) : M_TAB;
        if (pass == 1 && gid >= 32) break;
        const float t = (float)g * STEP;
        const int s0 = (int)ceilf(t - 2.0f);   // segments s0..s0+3 cover all w>0

        float partial = 0.0f;   // sum_j w_j * w2*tanh(.)   (this lane's h)
        float wb2 = 0.0f;       // sum_j w_j * b2[s_j]
        #pragma unroll
        for (int j = 0; j < 4; ++j) {
            const int s = s0 + j;
            const bool ok = ((unsigned)s < (unsigned)NS);
            const int sc = ok ? s : 0;
            // window = (1+cos(pi*d/2))/2 ; v_cos takes revolutions -> arg d/4
            const float c = __builtin_amdgcn_cosf((t - (float)s) * 0.25f);
            const float w = ok ? fmaf(0.5f, c, 0.5f) : 0.0f;

            const float w1v = W1[sc * NH + h];   // coalesced: h fast across lanes
            const float b1v = b1[sc * NH + h];
            const float w2v = W2[sc * NH + h];
            const float x = fmaf(t, w1v, b1v);
            const float e = __builtin_amdgcn_exp2f(x * C2L);      // e^(2x)
            const float r = __builtin_amdgcn_rcpf(e + 1.0f);
            // w2*tanh(x) = w2 - 2*w2*r
            partial = fmaf(w, fmaf(-2.0f * w2v, r, w2v), partial);
            wb2 = fmaf(w, b2[sc], wb2);
        }
        // reduce over the 32 h-lanes (xor<=16 stays within each 32-lane half)
        partial += __shfl_xor(partial, 1, 64);
        partial += __shfl_xor(partial, 2, 64);
        partial += __shfl_xor(partial, 4, 64);
        partial += __shfl_xor(partial, 8, 64);
        partial += __shfl_xor(partial, 16, 64);
        if (h == 0) table[g] = partial + wb2;
    }

    cg::this_grid().sync();

    // ---- phase 2: 1 point per thread, lerp from the 16 KB L2-hot table ----
    if (gid < N) {
        const float t = t_in[gid];
        const float u = t * INV_STEP;
        int i = (int)u;
        i = min(max(i, 0), M_TAB - 1);
        const float f = u - (float)i;
        const float y0 = table[i];
        const float y1 = table[i + 1];
        out[gid] = fmaf(f, y1 - y0, y0);
    }
}

extern "C" void kernel_launch(void* const* d_in, const int* in_sizes, int n_in,
                              void* d_out, int out_size, void* d_ws, size_t ws_size,
                              hipStream_t stream) {
    const float* t  = (const float*)d_in[0];
    const float* W1 = (const float*)d_in[1];
    const float* b1 = (const float*)d_in[2];
    const float* W2 = (const float*)d_in[3];
    const float* b2 = (const float*)d_in[4];
    float* outp = (float*)d_out;
    int N = in_sizes[0];
    float* table = (float*)d_ws;     // (M_TAB+1)*4 = 16388 B, rewritten each call

    void* args[] = {(void*)&t, (void*)&W1, (void*)&b1, (void*)&W2, (void*)&b2,
                    (void*)&table, (void*)&outp, (void*)&N};
    hipLaunchCooperativeKernel((void*)springnn_fused_kernel,
                               dim3(512), dim3(256), args, 0, stream);
}

// Round 13
// 11.576 us; speedup vs baseline: 4.6969x; 4.6969x over previous
//
#include <hip/hip_runtime.h>

#define NS 32
#define NH 32
#define M_TAB 1024                              // intervals over [0,31]
#define C2L 2.8853900817779268f                 // 2*log2(e): e^(2x) = 2^(C2L*x)
#define STEP (31.0f / (float)M_TAB)
#define INV_STEP ((float)M_TAB / 31.0f)
// table[k] = f((k-1)*STEP), k = 0..M_TAB+2  (one guard node each side)
#define TAB_NODES (M_TAB + 3)

// Kernel A: tabulate f at 1027 nodes (half-wave per node, lane = h).
// Guard nodes at t=-STEP and t=31+STEP evaluate fine: the masked segment
// logic zeroes out-of-range s. 129 blocks.
__global__ __launch_bounds__(256) void table_kernel(
    const float* __restrict__ W1,   // [S][1][H]
    const float* __restrict__ b1,   // [S][H]
    const float* __restrict__ W2,   // [S][H][1]
    const float* __restrict__ b2,   // [S][1]
    float* __restrict__ table)
{
    const int gid = blockIdx.x * 256 + threadIdx.x;
    const int g = gid >> 5;          // node index 0..TAB_NODES-1
    const int h = gid & 31;          // hidden unit (lane)
    if (g >= TAB_NODES) return;      // whole half-waves exit together
    const float t = (float)(g - 1) * STEP;
    const int s0 = (int)ceilf(t - 2.0f);   // segments s0..s0+3 cover all w>0

    float partial = 0.0f;   // sum_j w_j * w2*tanh(.)   (this lane's h)
    float wb2 = 0.0f;       // sum_j w_j * b2[s_j]
    #pragma unroll
    for (int j = 0; j < 4; ++j) {
        const int s = s0 + j;
        const bool ok = ((unsigned)s < (unsigned)NS);
        const int sc = ok ? s : 0;
        // window = (1+cos(pi*d/2))/2 ; v_cos takes revolutions -> arg d/4
        const float c = __builtin_amdgcn_cosf((t - (float)s) * 0.25f);
        const float w = ok ? fmaf(0.5f, c, 0.5f) : 0.0f;

        const float w1v = W1[sc * NH + h];   // coalesced: h fast across lanes
        const float b1v = b1[sc * NH + h];
        const float w2v = W2[sc * NH + h];
        const float x = fmaf(t, w1v, b1v);
        const float e = __builtin_amdgcn_exp2f(x * C2L);      // e^(2x)
        const float r = __builtin_amdgcn_rcpf(e + 1.0f);
        // w2*tanh(x) = w2 - 2*w2*r
        partial = fmaf(w, fmaf(-2.0f * w2v, r, w2v), partial);
        wb2 = fmaf(w, b2[sc], wb2);
    }
    // reduce over the 32 h-lanes (xor<=16 stays within each 32-lane half)
    partial += __shfl_xor(partial, 1, 64);
    partial += __shfl_xor(partial, 2, 64);
    partial += __shfl_xor(partial, 4, 64);
    partial += __shfl_xor(partial, 8, 64);
    partial += __shfl_xor(partial, 16, 64);
    if (h == 0) table[g] = partial + wb2;
}

// Kernel B: cubic Lagrange interpolation, 4 points per thread (float4 I/O).
// Table is 4 KB -> L1-resident. 128 blocks.
__global__ __launch_bounds__(256) void interp_kernel(
    const float* __restrict__ t_in, const float* __restrict__ table,
    float* __restrict__ out, int N)
{
    const int base = (blockIdx.x * 256 + threadIdx.x) * 4;
    if (base + 3 >= N) {   // generic tail (unused at N=131072)
        for (int n = base; n < N; ++n) {
            const float u0 = t_in[n] * INV_STEP;
            int i = min(max((int)u0, 0), M_TAB - 1);
            const float u = u0 - (float)i;
            const float p0 = table[i], p1 = table[i + 1];
            const float p2 = table[i + 2], p3 = table[i + 3];
            const float um1 = u - 1.f, um2 = u - 2.f, up1 = u + 1.f;
            const float a = um1 * um2, bq = up1 * u;
            out[n] = (u * a * (-1.f / 6.f)) * p0 + (0.5f * up1 * a) * p1
                   + (-0.5f * bq * um2) * p2 + (bq * um1 * (1.f / 6.f)) * p3;
        }
        return;
    }
    const float4 tv = *(const float4*)(t_in + base);
    float r[4];
    const float tt[4] = {tv.x, tv.y, tv.z, tv.w};
    #pragma unroll
    for (int k = 0; k < 4; ++k) {
        const float u0 = tt[k] * INV_STEP;
        int i = min(max((int)u0, 0), M_TAB - 1);
        const float u = u0 - (float)i;     // in [0,1): interp between nodes i+1,i+2
        const float p0 = table[i], p1 = table[i + 1];
        const float p2 = table[i + 2], p3 = table[i + 3];
        // Lagrange basis on {-1,0,1,2} at u
        const float um1 = u - 1.f, um2 = u - 2.f, up1 = u + 1.f;
        const float a = um1 * um2;         // (u-1)(u-2)
        const float bq = up1 * u;          // (u+1)u
        const float L0 = u * a * (-1.f / 6.f);
        const float L1 = 0.5f * up1 * a;
        const float L2 = -0.5f * bq * um2;
        const float L3 = bq * um1 * (1.f / 6.f);
        r[k] = (L0 * p0 + L1 * p1) + (L2 * p2 + L3 * p3);
    }
    *(float4*)(out + base) = make_float4(r[0], r[1], r[2], r[3]);
}

extern "C" void kernel_launch(void* const* d_in, const int* in_sizes, int n_in,
                              void* d_out, int out_size, void* d_ws, size_t ws_size,
                              hipStream_t stream) {
    const float* t  = (const float*)d_in[0];
    const float* W1 = (const float*)d_in[1];
    const float* b1 = (const float*)d_in[2];
    const float* W2 = (const float*)d_in[3];
    const float* b2 = (const float*)d_in[4];
    float* outp = (float*)d_out;
    const int N = in_sizes[0];

    float* table = (float*)d_ws;     // TAB_NODES*4 = 4108 B, rewritten each call

    const int blkA = (TAB_NODES * NH + 255) / 256;       // 129 blocks
    table_kernel<<<blkA, 256, 0, stream>>>(W1, b1, W2, b2, table);
    const int blkB = (N / 4 + 255) / 256;                // 128 blocks
    interp_kernel<<<blkB, 256, 0, stream>>>(t, table, outp, N);
}